// Round 15
// baseline (447.027 us; speedup 1.0000x reference)
//
#include <hip/hip_runtime.h>

static constexpr float NEG_SLOPE = 0.01f;
static constexpr float BN_EPS = 1e-5f;

using f16 = _Float16;
using f16x4 = __attribute__((ext_vector_type(4))) _Float16;
using f16x8 = __attribute__((ext_vector_type(8))) _Float16;
using f32x4 = __attribute__((ext_vector_type(4))) float;

// ---------------------------------------------------------------------------
__global__ __launch_bounds__(256) void sentinel_kernel(float* out, int m, float val) {
  int i = blockIdx.x * 256 + threadIdx.x;
  if (i < m) out[i] = val;
}

// zero deg (n ints) + stats (256 floats) + the zero-row of g (row n, 128 B)
__global__ __launch_bounds__(256) void zero_kernel(int* __restrict__ deg,
                                                   float* __restrict__ stats,
                                                   unsigned int* __restrict__ gzero, int n) {
  int stride = gridDim.x * blockDim.x;
  for (int i = blockIdx.x * blockDim.x + threadIdx.x; i < n; i += stride) deg[i] = 0;
  if (blockIdx.x == 0 && threadIdx.x < 256) stats[threadIdx.x] = 0.f;
  if (blockIdx.x == 0 && threadIdx.x < 32) gzero[threadIdx.x] = 0u;
}

// deg[v] += 1 per incoming edge; 4 independent edges per thread
__global__ __launch_bounds__(256) void deg_kernel(const int* __restrict__ col,
                                                  int* __restrict__ deg, int E) {
  int t = blockIdx.x * 256 + threadIdx.x;
  int S = gridDim.x * 256;
  int e0 = t, e1 = t + S, e2 = t + 2 * S, e3 = t + 3 * S;
  int v0 = (e0 < E) ? col[e0] : -1;
  int v1 = (e1 < E) ? col[e1] : -1;
  int v2 = (e2 < E) ? col[e2] : -1;
  int v3 = (e3 < E) ? col[e3] : -1;
  if (v0 >= 0) atomicAdd(&deg[v0], 1);
  if (v1 >= 0) atomicAdd(&deg[v1], 1);
  if (v2 >= 0) atomicAdd(&deg[v2], 1);
  if (v3 >= 0) atomicAdd(&deg[v3], 1);
}

// ---------------------------------------------------------------------------
// 3-phase exclusive scan over padded degrees pd=(d+1+7)&~7 (self included).
__global__ __launch_bounds__(256) void scan_partial(const int* __restrict__ deg,
                                                    int* __restrict__ partial, int n) {
  int i = blockIdx.x * 256 + threadIdx.x;
  int d = (i < n) ? deg[i] : 0;
  int pd = (i < n) ? ((d + 8) & ~7) : 0;
  __shared__ int s[256];
  s[threadIdx.x] = pd;
  __syncthreads();
  for (int off = 128; off; off >>= 1) {
    if (threadIdx.x < off) s[threadIdx.x] += s[threadIdx.x + off];
    __syncthreads();
  }
  if (threadIdx.x == 0) partial[blockIdx.x] = s[0];
}

__global__ __launch_bounds__(256) void scan_top(int* partial, int nb) {
  __shared__ int s[256];
  __shared__ int carry_s;
  if (threadIdx.x == 0) carry_s = 0;
  __syncthreads();
  for (int base = 0; base < nb; base += 256) {
    int i = base + threadIdx.x;
    int v = (i < nb) ? partial[i] : 0;
    s[threadIdx.x] = v;
    __syncthreads();
    for (int off = 1; off < 256; off <<= 1) {
      int t = (threadIdx.x >= off) ? s[threadIdx.x - off] : 0;
      __syncthreads();
      s[threadIdx.x] += t;
      __syncthreads();
    }
    int inc = s[threadIdx.x];
    int tot = s[255];
    int carry = carry_s;
    if (i < nb) partial[i] = carry + inc - v;
    __syncthreads();
    if (threadIdx.x == 0) carry_s = carry + tot;
    __syncthreads();
  }
}

// pstart/cursor/dis + write self-loop & pad entries into csr
__global__ __launch_bounds__(256) void scan_final(const int* __restrict__ deg,
                                                  const int* __restrict__ partial,
                                                  int* __restrict__ pstart,
                                                  int* __restrict__ cursor,
                                                  int* __restrict__ csr,
                                                  float* __restrict__ dis, int n) {
  int i = blockIdx.x * 256 + threadIdx.x;
  int d = (i < n) ? deg[i] : 0;
  int pd = (i < n) ? ((d + 8) & ~7) : 0;
  __shared__ int s[256];
  s[threadIdx.x] = pd;
  __syncthreads();
  for (int off = 1; off < 256; off <<= 1) {
    int t = (threadIdx.x >= off) ? s[threadIdx.x - off] : 0;
    __syncthreads();
    s[threadIdx.x] += t;
    __syncthreads();
  }
  if (i < n) {
    int incl = partial[blockIdx.x] + s[threadIdx.x];
    int ps = incl - pd;
    pstart[i] = ps;
    cursor[i] = ps + d;          // neighbors land in [ps, ps+d)
    dis[i] = rsqrtf((float)(d + 1));
    csr[ps + d] = i;             // self loop
    for (int j = d + 1; j < pd; ++j) csr[ps + j] = n;  // pads -> zero row
    if (i == n - 1) pstart[n] = incl;
  }
}

// ---------------------------------------------------------------------------
// bucket counts: bcnt[b] = sum deg[b*32 .. b*32+31]
__global__ __launch_bounds__(256) void bucket_count(const int* __restrict__ deg,
                                                    int* __restrict__ bcnt, int n, int NBK) {
  int b = blockIdx.x * 256 + threadIdx.x;
  if (b >= NBK) return;
  int v0 = b << 5;
  int v1 = v0 + 32 < n ? v0 + 32 : n;
  int s = 0;
  for (int v = v0; v < v1; ++v) s += deg[v];
  bcnt[b] = s;
}

// single-block exclusive scan of bcnt -> bstart & bcur; bstart[NBK]=E
__global__ __launch_bounds__(256) void scan_buckets(const int* __restrict__ bcnt,
                                                    int* __restrict__ bstart,
                                                    int* __restrict__ bcur, int NBK, int E) {
  __shared__ int s[256];
  __shared__ int carry_s;
  if (threadIdx.x == 0) carry_s = 0;
  __syncthreads();
  for (int base = 0; base < NBK; base += 256) {
    int i = base + threadIdx.x;
    int v = (i < NBK) ? bcnt[i] : 0;
    s[threadIdx.x] = v;
    __syncthreads();
    for (int off = 1; off < 256; off <<= 1) {
      int t = (threadIdx.x >= off) ? s[threadIdx.x - off] : 0;
      __syncthreads();
      s[threadIdx.x] += t;
      __syncthreads();
    }
    int inc = s[threadIdx.x];
    int tot = s[255];
    int carry = carry_s;
    if (i < NBK) {
      int st = carry + inc - v;
      bstart[i] = st;
      bcur[i] = st;
    }
    __syncthreads();
    if (threadIdx.x == 0) carry_s = carry + tot;
    __syncthreads();
  }
  if (threadIdx.x == 0) bstart[NBK] = E;
}

// pass 1: append edges into col-range buckets (append-contiguous writes)
__global__ __launch_bounds__(256) void bucket_scatter(
    const int* __restrict__ row, const int* __restrict__ colv,
    int* __restrict__ bcur, int2* __restrict__ staging, int E) {
  int t = blockIdx.x * 256 + threadIdx.x;
  int S = gridDim.x * 256;
#pragma unroll
  for (int j = 0; j < 4; ++j) {
    int e = t + j * S;
    if (e < E) {
      int c = colv[e];
      int r = row[e];
      int pos = atomicAdd(&bcur[c >> 5], 1);
      staging[pos] = make_int2(r, c);
    }
  }
}

// pass 2: one wave per bucket; csr writes confined to a ~2KB window (L2-hot)
__global__ __launch_bounds__(256) void bucket_fill(
    const int2* __restrict__ staging, const int* __restrict__ bstart,
    int* __restrict__ cursor, int* __restrict__ csr, int NBK) {
  int wid = (blockIdx.x * 256 + threadIdx.x) >> 6;
  int lane = threadIdx.x & 63;
  int nw = (gridDim.x * 256) >> 6;
  for (int b = wid; b < NBK; b += nw) {
    int s = bstart[b];
    int epos = bstart[b + 1];
    for (int i = s + lane; i < epos; i += 64) {
      int2 rc = staging[i];
      int o = atomicSub(&cursor[rc.y], 1) - 1;
      csr[o] = rc.x;
    }
  }
}

// ---------------------------------------------------------------------------
// MFMA GEMM: g[r,c] = ((A[r,:](*sc) @ W[:,c]) + cadd[c]) * dis[r], fp16 out.
template <int KD, bool FOLD, bool A_HALF>
__global__ __launch_bounds__(256) void mfma_gemm(
    const void* __restrict__ Aptr, const float* __restrict__ W,
    const float* __restrict__ sc, const float* __restrict__ cadd,
    const float* __restrict__ dis, f16* __restrict__ g, int n) {
  constexpr int NKT = KD / 16;
  const int lane = threadIdx.x & 63;
  const int wq = threadIdx.x >> 6;
  const int lr = lane & 15;
  const int kb = (lane >> 4) * 4;

  f16x4 bfrag[NKT][4];
#pragma unroll
  for (int kt = 0; kt < NKT; ++kt)
#pragma unroll
    for (int ct = 0; ct < 4; ++ct) {
#pragma unroll
      for (int j = 0; j < 4; ++j) {
        int k = kt * 16 + kb + j;
        float w = W[k * 64 + ct * 16 + lr];
        if (FOLD) w *= sc[k];
        bfrag[kt][ct][j] = (f16)w;
      }
    }
  float cl[4];
#pragma unroll
  for (int ct = 0; ct < 4; ++ct) cl[ct] = FOLD ? cadd[ct * 16 + lr] : 0.f;

  const int ntiles = (n + 15) >> 4;
  for (int t = blockIdx.x * 4 + wq; t < ntiles; t += gridDim.x * 4) {
    const int r0 = t << 4;
    int arow = r0 + lr;
    if (arow >= n) arow = n - 1;
    f16x4 afrag[NKT];
    if (A_HALF) {
      const f16* Ah = (const f16*)Aptr;
#pragma unroll
      for (int kt = 0; kt < NKT; ++kt)
        afrag[kt] = *reinterpret_cast<const f16x4*>(Ah + (size_t)arow * KD + kt * 16 + kb);
    } else {
      const float* Af = (const float*)Aptr;
#pragma unroll
      for (int kt = 0; kt < NKT; ++kt) {
        f32x4 xa = *reinterpret_cast<const f32x4*>(Af + (size_t)arow * KD + kt * 16 + kb);
        f16x4 a;
        a[0] = (f16)xa[0]; a[1] = (f16)xa[1]; a[2] = (f16)xa[2]; a[3] = (f16)xa[3];
        afrag[kt] = a;
      }
    }
    f32x4 acc[4];
#pragma unroll
    for (int ct = 0; ct < 4; ++ct) acc[ct] = (f32x4){0.f, 0.f, 0.f, 0.f};
#pragma unroll
    for (int kt = 0; kt < NKT; ++kt)
#pragma unroll
      for (int ct = 0; ct < 4; ++ct)
        acc[ct] = __builtin_amdgcn_mfma_f32_16x16x16f16(afrag[kt], bfrag[kt][ct], acc[ct], 0, 0, 0);
    if (r0 + 16 <= n) {
#pragma unroll
      for (int v = 0; v < 4; ++v) {
        int grow = r0 + (lane >> 4) * 4 + v;
        float dv = dis[grow];
#pragma unroll
        for (int ct = 0; ct < 4; ++ct)
          g[(size_t)grow * 64 + ct * 16 + lr] = (f16)((acc[ct][v] + cl[ct]) * dv);
      }
    } else {
      for (int v = 0; v < 4; ++v) {
        int grow = r0 + (lane >> 4) * 4 + v;
        if (grow < n) {
          float dv = dis[grow];
          for (int ct = 0; ct < 4; ++ct)
            g[(size_t)grow * 64 + ct * 16 + lr] = (f16)((acc[ct][v] + cl[ct]) * dv);
        }
      }
    }
  }
}

// ---------------------------------------------------------------------------
// Octet gather: 8 lanes x 16B (f16x8) per row -> one instr gathers 8 rows.
// CSR includes self-loop and zero-row pads; no masking in the inner loop.
// t[v] = leaky(dis[v]*sum + bias) stored f16; stats via block reduce + atomics.
__global__ __launch_bounds__(256) void gather_post3(
    const f16* __restrict__ g, const int* __restrict__ csr,
    const int* __restrict__ pstart, const float* __restrict__ dis,
    const float* __restrict__ bias, f16* __restrict__ t_out,
    float* __restrict__ stats, int n, int span) {
  const int tid = threadIdx.x;
  const int w = tid >> 6;
  const int lane = tid & 63;
  const int grp = lane >> 3;  // row slot 0..7
  const int q = lane & 7;     // 16B sub-slot: features q*8 .. q*8+7
  float bias8[8];
#pragma unroll
  for (int j = 0; j < 8; ++j) bias8[j] = bias[q * 8 + j];
  float sum8[8], sq8[8];
#pragma unroll
  for (int j = 0; j < 8; ++j) { sum8[j] = 0.f; sq8[j] = 0.f; }

  const int v0 = blockIdx.x * span;
  const int vend = (v0 + span < n) ? v0 + span : n;
  for (int v = v0 + w; v < vend; v += 4) {
    const int ps = pstart[v];
    const int pe = pstart[v + 1];
    float acc[8];
#pragma unroll
    for (int j = 0; j < 8; ++j) acc[j] = 0.f;
    int e = ps;
    for (; e + 8 < pe; e += 16) {
      int ua = csr[e + grp];
      int ub = csr[e + 8 + grp];
      f16x8 da = *reinterpret_cast<const f16x8*>(g + (size_t)ua * 64 + q * 8);
      f16x8 db = *reinterpret_cast<const f16x8*>(g + (size_t)ub * 64 + q * 8);
#pragma unroll
      for (int j = 0; j < 8; ++j) acc[j] += (float)da[j] + (float)db[j];
    }
    if (e < pe) {
      int u = csr[e + grp];
      f16x8 d = *reinterpret_cast<const f16x8*>(g + (size_t)u * 64 + q * 8);
#pragma unroll
      for (int j = 0; j < 8; ++j) acc[j] += (float)d[j];
    }
    // reduce across the 8 row-groups (xor over lane bits 3..5)
#pragma unroll
    for (int j = 0; j < 8; ++j) acc[j] += __shfl_xor(acc[j], 8);
#pragma unroll
    for (int j = 0; j < 8; ++j) acc[j] += __shfl_xor(acc[j], 16);
#pragma unroll
    for (int j = 0; j < 8; ++j) acc[j] += __shfl_xor(acc[j], 32);
    if (grp == 0) {
      float dv = dis[v];
      f16x8 o;
#pragma unroll
      for (int j = 0; j < 8; ++j) {
        float x = dv * acc[j] + bias8[j];
        x = (x > 0.f) ? x : NEG_SLOPE * x;
        o[j] = (f16)x;
        sum8[j] += x;
        sq8[j] += x * x;
      }
      *reinterpret_cast<f16x8*>(t_out + (size_t)v * 64 + q * 8) = o;
    }
  }
  __shared__ float sm[4][128];
  if (grp == 0) {
#pragma unroll
    for (int j = 0; j < 8; ++j) {
      sm[w][q * 8 + j] = sum8[j];
      sm[w][64 + q * 8 + j] = sq8[j];
    }
  }
  __syncthreads();
  if (tid < 128)
    atomicAdd(&stats[tid], sm[0][tid] + sm[1][tid] + sm[2][tid] + sm[3][tid]);
}

// ---------------------------------------------------------------------------
// BN fold params from stats: sc, sh; optionally c[j] = sum_k sh[k]*W[k,j].
__global__ __launch_bounds__(64) void bnparam_kernel(
    const float* __restrict__ stats, const float* __restrict__ gamma,
    const float* __restrict__ beta, const float* __restrict__ W,
    float* __restrict__ outp, int n, int withC) {
  int d = threadIdx.x;
  __shared__ float ssh[64];
  float inv_n = 1.0f / (float)n;
  float mu = stats[d] * inv_n;
  float var = stats[64 + d] * inv_n - mu * mu;
  float r = rsqrtf(var + BN_EPS);
  float s = gamma[d] * r;
  float sh = beta[d] - mu * s;
  outp[d] = s;
  outp[64 + d] = sh;
  ssh[d] = sh;
  __syncthreads();
  if (withC) {
    float c = 0.f;
    for (int k = 0; k < 64; ++k) c = fmaf(ssh[k], W[k * 64 + d], c);
    outp[128 + d] = c;
  }
}

// fused: h_sel = t[idx]*sc1+sh1 (t is f16); out2 = sigmoid(h_sel@Wm+bm)
__global__ __launch_bounds__(256) void selmlp_kernel(
    const f16* __restrict__ t, const int* __restrict__ idx,
    const float* __restrict__ bnp, const float* __restrict__ Wm,
    const float* __restrict__ bm, float* __restrict__ out,
    float* __restrict__ out2, int K) {
  const int lane = threadIdx.x & 63;
  int w = (blockIdx.x * 256 + threadIdx.x) >> 6;
  if (w >= K) return;
  int v = idx[w];
  float hv = fmaf((float)t[(size_t)v * 64 + lane], bnp[lane], bnp[64 + lane]);
  out[(size_t)w * 64 + lane] = hv;
#pragma unroll
  for (int j = 0; j < 5; ++j) {
    float p = hv * Wm[lane * 5 + j];
#pragma unroll
    for (int off = 32; off; off >>= 1) p += __shfl_xor(p, off);
    if (lane == 0) out2[(size_t)w * 5 + j] = 1.f / (1.f + expf(-(p + bm[j])));
  }
}

// ---------------------------------------------------------------------------
extern "C" void kernel_launch(void* const* d_in, const int* in_sizes, int n_in,
                              void* d_out, int out_size, void* d_ws, size_t ws_size,
                              hipStream_t stream) {
  const float* x      = (const float*)d_in[0];
  const int*   eidx   = (const int*)d_in[1];
  const int*   idx    = (const int*)d_in[2];
  const float* W0     = (const float*)d_in[3];
  const float* b0     = (const float*)d_in[4];
  const float* gamma0 = (const float*)d_in[5];
  const float* beta0  = (const float*)d_in[6];
  const float* W1     = (const float*)d_in[7];
  const float* b1     = (const float*)d_in[8];
  const float* gamma1 = (const float*)d_in[9];
  const float* beta1  = (const float*)d_in[10];
  const float* Wm     = (const float*)d_in[11];
  const float* bm     = (const float*)d_in[12];

  const int n = in_sizes[0] / 128;
  const int E = in_sizes[1] / 2;
  const int K = in_sizes[2];
  const int* erow = eidx;      // sources  (edge_index[0])
  const int* ecol = eidx + E;  // targets  (edge_index[1])
  const int nb = (n + 255) / 256;
  const int NBK = (n + 31) >> 5;                        // col buckets (32 nodes)
  const size_t Ecap = (size_t)E + 9 * (size_t)n + 64;   // padded csr capacity
  const int NB = 1024;                                  // gather blocks

  size_t needed = ((size_t)n + 1) * 64 * 2      // gh (+zero row)
                + (size_t)n * 64 * 2            // t0h (layer act, reused)
                + (size_t)n * 4 * 3             // dis, deg, cursor
                + ((size_t)n + 4) * 4           // pstart
                + Ecap * 4                      // csr (padded)
                + (size_t)E * 8                 // staging (int2)
                + (size_t)(NBK + 2) * 4 * 3     // bcnt, bstart, bcur
                + 256 * 4 + 320 * 4             // stats + bnp
                + (size_t)(nb + 4) * 4;         // partial
  if (ws_size < needed) {
    sentinel_kernel<<<dim3((out_size + 255) / 256), dim3(256), 0, stream>>>(
        (float*)d_out, out_size, 1e6f);
    return;
  }
  f16*   gh     = (f16*)d_ws;                     // (n+1)*64 fp16
  f16*   t0h    = gh + ((size_t)n + 1) * 64;      // n*64 fp16 (both layers' act)
  float* dis    = (float*)(t0h + (size_t)n * 64); // n
  int*   deg    = (int*)(dis + n);                // n
  int*   pstart = deg + n;                        // n+4
  int*   cursor = pstart + (n + 4);               // n
  int*   csr    = cursor + n;                     // Ecap
  int2*  staging = (int2*)(csr + Ecap);           // E (8B-aligned)
  int*   bcnt   = (int*)(staging + E);            // NBK+2
  int*   bstart = bcnt + (NBK + 2);               // NBK+2
  int*   bcur   = bstart + (NBK + 2);             // NBK+2
  float* stats  = (float*)(bcur + (NBK + 2));     // 256
  float* bnp    = stats + 256;                    // 320
  int*   partial = (int*)(bnp + 320);             // nb+4

  dim3 blk(256);
  const int eb4 = (E + 1023) / 1024;
  const int span = (n + NB - 1) / NB;
  // ---- graph preprocessing ----
  zero_kernel<<<dim3(nb), blk, 0, stream>>>(deg, stats, (unsigned int*)(gh + (size_t)n * 64), n);
  deg_kernel<<<dim3(eb4), blk, 0, stream>>>(ecol, deg, E);
  scan_partial<<<dim3(nb), blk, 0, stream>>>(deg, partial, n);
  scan_top<<<dim3(1), blk, 0, stream>>>(partial, nb);
  scan_final<<<dim3(nb), blk, 0, stream>>>(deg, partial, pstart, cursor, csr, dis, n);
  bucket_count<<<dim3((NBK + 255) / 256), blk, 0, stream>>>(deg, bcnt, n, NBK);
  scan_buckets<<<dim3(1), blk, 0, stream>>>(bcnt, bstart, bcur, NBK, E);
  bucket_scatter<<<dim3(eb4), blk, 0, stream>>>(erow, ecol, bcur, staging, E);
  bucket_fill<<<dim3(256), blk, 0, stream>>>(staging, bstart, cursor, csr, NBK);

  // ---- layer 0 ----
  mfma_gemm<128, false, false><<<dim3(392), blk, 0, stream>>>(
      x, W0, nullptr, nullptr, dis, gh, n);
  gather_post3<<<dim3(NB), blk, 0, stream>>>(gh, csr, pstart, dis, b0, t0h, stats, n, span);
  bnparam_kernel<<<dim3(1), dim3(64), 0, stream>>>(stats, gamma0, beta0, W1, bnp, n, 1);
  // ---- layer 1 (BN0 folded into GEMM) ----
  mfma_gemm<64, true, true><<<dim3(392), blk, 0, stream>>>(
      t0h, W1, bnp, bnp + 128, dis, gh, n);
  gather_post3<<<dim3(NB), blk, 0, stream>>>(gh, csr, pstart, dis, b1, t0h, stats + 128, n, span);
  bnparam_kernel<<<dim3(1), dim3(64), 0, stream>>>(
      stats + 128, gamma1, beta1, nullptr, bnp + 192, n, 0);
  // ---- select + MLP (BN1 folded in) ----
  selmlp_kernel<<<dim3((K + 3) / 4), blk, 0, stream>>>(
      t0h, idx, bnp + 192, Wm, bm, (float*)d_out, (float*)d_out + (size_t)K * 64, K);
}

// Round 16
// 335.539 us; speedup vs baseline: 1.3323x; 1.3323x over previous
//
#include <hip/hip_runtime.h>

static constexpr float NEG_SLOPE = 0.01f;
static constexpr float BN_EPS = 1e-5f;

using f16 = _Float16;
using f16x4 = __attribute__((ext_vector_type(4))) _Float16;
using f16x8 = __attribute__((ext_vector_type(8))) _Float16;
using f32x4 = __attribute__((ext_vector_type(4))) float;

// ---------------------------------------------------------------------------
__global__ __launch_bounds__(256) void sentinel_kernel(float* out, int m, float val) {
  int i = blockIdx.x * 256 + threadIdx.x;
  if (i < m) out[i] = val;
}

// zero deg (n ints) + stats (256 floats) + the zero-row of g (row n, 128 B)
__global__ __launch_bounds__(256) void zero_kernel(int* __restrict__ deg,
                                                   float* __restrict__ stats,
                                                   unsigned int* __restrict__ gzero, int n) {
  int stride = gridDim.x * blockDim.x;
  for (int i = blockIdx.x * blockDim.x + threadIdx.x; i < n; i += stride) deg[i] = 0;
  if (blockIdx.x == 0 && threadIdx.x < 256) stats[threadIdx.x] = 0.f;
  if (blockIdx.x == 0 && threadIdx.x < 32) gzero[threadIdx.x] = 0u;
}

// deg[v] += 1 per incoming edge; 4 independent edges per thread
__global__ __launch_bounds__(256) void deg_kernel(const int* __restrict__ col,
                                                  int* __restrict__ deg, int E) {
  int t = blockIdx.x * 256 + threadIdx.x;
  int S = gridDim.x * 256;
  int e0 = t, e1 = t + S, e2 = t + 2 * S, e3 = t + 3 * S;
  int v0 = (e0 < E) ? col[e0] : -1;
  int v1 = (e1 < E) ? col[e1] : -1;
  int v2 = (e2 < E) ? col[e2] : -1;
  int v3 = (e3 < E) ? col[e3] : -1;
  if (v0 >= 0) atomicAdd(&deg[v0], 1);
  if (v1 >= 0) atomicAdd(&deg[v1], 1);
  if (v2 >= 0) atomicAdd(&deg[v2], 1);
  if (v3 >= 0) atomicAdd(&deg[v3], 1);
}

// ---------------------------------------------------------------------------
// 3-phase exclusive scan over padded degrees pd=(d+1+7)&~7 (self included).
__global__ __launch_bounds__(256) void scan_partial(const int* __restrict__ deg,
                                                    int* __restrict__ partial, int n) {
  int i = blockIdx.x * 256 + threadIdx.x;
  int d = (i < n) ? deg[i] : 0;
  int pd = (i < n) ? ((d + 8) & ~7) : 0;
  __shared__ int s[256];
  s[threadIdx.x] = pd;
  __syncthreads();
  for (int off = 128; off; off >>= 1) {
    if (threadIdx.x < off) s[threadIdx.x] += s[threadIdx.x + off];
    __syncthreads();
  }
  if (threadIdx.x == 0) partial[blockIdx.x] = s[0];
}

__global__ __launch_bounds__(256) void scan_top(int* partial, int nb) {
  __shared__ int s[256];
  __shared__ int carry_s;
  if (threadIdx.x == 0) carry_s = 0;
  __syncthreads();
  for (int base = 0; base < nb; base += 256) {
    int i = base + threadIdx.x;
    int v = (i < nb) ? partial[i] : 0;
    s[threadIdx.x] = v;
    __syncthreads();
    for (int off = 1; off < 256; off <<= 1) {
      int t = (threadIdx.x >= off) ? s[threadIdx.x - off] : 0;
      __syncthreads();
      s[threadIdx.x] += t;
      __syncthreads();
    }
    int inc = s[threadIdx.x];
    int tot = s[255];
    int carry = carry_s;
    if (i < nb) partial[i] = carry + inc - v;
    __syncthreads();
    if (threadIdx.x == 0) carry_s = carry + tot;
    __syncthreads();
  }
}

// pstart/cursor/dis + write self-loop & pad entries into csr
__global__ __launch_bounds__(256) void scan_final(const int* __restrict__ deg,
                                                  const int* __restrict__ partial,
                                                  int* __restrict__ pstart,
                                                  int* __restrict__ cursor,
                                                  int* __restrict__ csr,
                                                  float* __restrict__ dis, int n) {
  int i = blockIdx.x * 256 + threadIdx.x;
  int d = (i < n) ? deg[i] : 0;
  int pd = (i < n) ? ((d + 8) & ~7) : 0;
  __shared__ int s[256];
  s[threadIdx.x] = pd;
  __syncthreads();
  for (int off = 1; off < 256; off <<= 1) {
    int t = (threadIdx.x >= off) ? s[threadIdx.x - off] : 0;
    __syncthreads();
    s[threadIdx.x] += t;
    __syncthreads();
  }
  if (i < n) {
    int incl = partial[blockIdx.x] + s[threadIdx.x];
    int ps = incl - pd;
    pstart[i] = ps;
    cursor[i] = ps + d;          // neighbors land in [ps, ps+d)
    dis[i] = rsqrtf((float)(d + 1));
    csr[ps + d] = i;             // self loop
    for (int j = d + 1; j < pd; ++j) csr[ps + j] = n;  // pads -> zero row
    if (i == n - 1) pstart[n] = incl;
  }
}

// csr[--cursor[v]] = row[e]; 8 independent edges per thread
__global__ __launch_bounds__(256) void fill_kernel(
    const int* __restrict__ row, const int* __restrict__ colv,
    int* __restrict__ cursor, int* __restrict__ csr, int E) {
  int t = blockIdx.x * 256 + threadIdx.x;
  int S = gridDim.x * 256;
  int vv[8], rr[8], oo[8];
  bool bb[8];
#pragma unroll
  for (int j = 0; j < 8; ++j) {
    int e = t + j * S;
    bb[j] = e < E;
    if (bb[j]) { vv[j] = colv[e]; rr[j] = row[e]; }
  }
#pragma unroll
  for (int j = 0; j < 8; ++j)
    if (bb[j]) oo[j] = atomicSub(&cursor[vv[j]], 1) - 1;
#pragma unroll
  for (int j = 0; j < 8; ++j)
    if (bb[j]) csr[oo[j]] = rr[j];
}

// ---------------------------------------------------------------------------
// MFMA GEMM: g[r,c] = ((A[r,:](*sc) @ W[:,c]) + cadd[c]) * dis[r], fp16 out.
// Grid kept small (~4 tiles/wave) so the 128-load B-fragment prologue
// amortizes over several tiles.
template <int KD, bool FOLD, bool A_HALF>
__global__ __launch_bounds__(256) void mfma_gemm(
    const void* __restrict__ Aptr, const float* __restrict__ W,
    const float* __restrict__ sc, const float* __restrict__ cadd,
    const float* __restrict__ dis, f16* __restrict__ g, int n) {
  constexpr int NKT = KD / 16;
  const int lane = threadIdx.x & 63;
  const int wq = threadIdx.x >> 6;
  const int lr = lane & 15;
  const int kb = (lane >> 4) * 4;

  f16x4 bfrag[NKT][4];
#pragma unroll
  for (int kt = 0; kt < NKT; ++kt)
#pragma unroll
    for (int ct = 0; ct < 4; ++ct) {
#pragma unroll
      for (int j = 0; j < 4; ++j) {
        int k = kt * 16 + kb + j;
        float w = W[k * 64 + ct * 16 + lr];
        if (FOLD) w *= sc[k];
        bfrag[kt][ct][j] = (f16)w;
      }
    }
  float cl[4];
#pragma unroll
  for (int ct = 0; ct < 4; ++ct) cl[ct] = FOLD ? cadd[ct * 16 + lr] : 0.f;

  const int ntiles = (n + 15) >> 4;
  for (int t = blockIdx.x * 4 + wq; t < ntiles; t += gridDim.x * 4) {
    const int r0 = t << 4;
    int arow = r0 + lr;
    if (arow >= n) arow = n - 1;
    f16x4 afrag[NKT];
    if (A_HALF) {
      const f16* Ah = (const f16*)Aptr;
#pragma unroll
      for (int kt = 0; kt < NKT; ++kt)
        afrag[kt] = *reinterpret_cast<const f16x4*>(Ah + (size_t)arow * KD + kt * 16 + kb);
    } else {
      const float* Af = (const float*)Aptr;
#pragma unroll
      for (int kt = 0; kt < NKT; ++kt) {
        f32x4 xa = *reinterpret_cast<const f32x4*>(Af + (size_t)arow * KD + kt * 16 + kb);
        f16x4 a;
        a[0] = (f16)xa[0]; a[1] = (f16)xa[1]; a[2] = (f16)xa[2]; a[3] = (f16)xa[3];
        afrag[kt] = a;
      }
    }
    f32x4 acc[4];
#pragma unroll
    for (int ct = 0; ct < 4; ++ct) acc[ct] = (f32x4){0.f, 0.f, 0.f, 0.f};
#pragma unroll
    for (int kt = 0; kt < NKT; ++kt)
#pragma unroll
      for (int ct = 0; ct < 4; ++ct)
        acc[ct] = __builtin_amdgcn_mfma_f32_16x16x16f16(afrag[kt], bfrag[kt][ct], acc[ct], 0, 0, 0);
    if (r0 + 16 <= n) {
#pragma unroll
      for (int v = 0; v < 4; ++v) {
        int grow = r0 + (lane >> 4) * 4 + v;
        float dv = dis[grow];
#pragma unroll
        for (int ct = 0; ct < 4; ++ct)
          g[(size_t)grow * 64 + ct * 16 + lr] = (f16)((acc[ct][v] + cl[ct]) * dv);
      }
    } else {
      for (int v = 0; v < 4; ++v) {
        int grow = r0 + (lane >> 4) * 4 + v;
        if (grow < n) {
          float dv = dis[grow];
          for (int ct = 0; ct < 4; ++ct)
            g[(size_t)grow * 64 + ct * 16 + lr] = (f16)((acc[ct][v] + cl[ct]) * dv);
        }
      }
    }
  }
}

// ---------------------------------------------------------------------------
// Octet gather: 8 lanes x 16B (f16x8) per row -> one instr gathers 8 rows.
// CSR includes self-loop and zero-row pads; no masking in the inner loop.
// t[v] = leaky(dis[v]*sum + bias) stored f16; stats via block reduce + atomics.
__global__ __launch_bounds__(256) void gather_post3(
    const f16* __restrict__ g, const int* __restrict__ csr,
    const int* __restrict__ pstart, const float* __restrict__ dis,
    const float* __restrict__ bias, f16* __restrict__ t_out,
    float* __restrict__ stats, int n, int span) {
  const int tid = threadIdx.x;
  const int w = tid >> 6;
  const int lane = tid & 63;
  const int grp = lane >> 3;  // row slot 0..7
  const int q = lane & 7;     // 16B sub-slot: features q*8 .. q*8+7
  float bias8[8];
#pragma unroll
  for (int j = 0; j < 8; ++j) bias8[j] = bias[q * 8 + j];
  float sum8[8], sq8[8];
#pragma unroll
  for (int j = 0; j < 8; ++j) { sum8[j] = 0.f; sq8[j] = 0.f; }

  const int v0 = blockIdx.x * span;
  const int vend = (v0 + span < n) ? v0 + span : n;
  for (int v = v0 + w; v < vend; v += 4) {
    const int ps = pstart[v];
    const int pe = pstart[v + 1];
    float acc[8];
#pragma unroll
    for (int j = 0; j < 8; ++j) acc[j] = 0.f;
    int e = ps;
    for (; e + 8 < pe; e += 16) {
      int ua = csr[e + grp];
      int ub = csr[e + 8 + grp];
      f16x8 da = *reinterpret_cast<const f16x8*>(g + (size_t)ua * 64 + q * 8);
      f16x8 db = *reinterpret_cast<const f16x8*>(g + (size_t)ub * 64 + q * 8);
#pragma unroll
      for (int j = 0; j < 8; ++j) acc[j] += (float)da[j] + (float)db[j];
    }
    if (e < pe) {
      int u = csr[e + grp];
      f16x8 d = *reinterpret_cast<const f16x8*>(g + (size_t)u * 64 + q * 8);
#pragma unroll
      for (int j = 0; j < 8; ++j) acc[j] += (float)d[j];
    }
    // reduce across the 8 row-groups (xor over lane bits 3..5)
#pragma unroll
    for (int j = 0; j < 8; ++j) acc[j] += __shfl_xor(acc[j], 8);
#pragma unroll
    for (int j = 0; j < 8; ++j) acc[j] += __shfl_xor(acc[j], 16);
#pragma unroll
    for (int j = 0; j < 8; ++j) acc[j] += __shfl_xor(acc[j], 32);
    if (grp == 0) {
      float dv = dis[v];
      f16x8 o;
#pragma unroll
      for (int j = 0; j < 8; ++j) {
        float x = dv * acc[j] + bias8[j];
        x = (x > 0.f) ? x : NEG_SLOPE * x;
        o[j] = (f16)x;
        sum8[j] += x;
        sq8[j] += x * x;
      }
      *reinterpret_cast<f16x8*>(t_out + (size_t)v * 64 + q * 8) = o;
    }
  }
  __shared__ float sm[4][128];
  if (grp == 0) {
#pragma unroll
    for (int j = 0; j < 8; ++j) {
      sm[w][q * 8 + j] = sum8[j];
      sm[w][64 + q * 8 + j] = sq8[j];
    }
  }
  __syncthreads();
  if (tid < 128)
    atomicAdd(&stats[tid], sm[0][tid] + sm[1][tid] + sm[2][tid] + sm[3][tid]);
}

// ---------------------------------------------------------------------------
// BN fold params from stats: sc, sh; optionally c[j] = sum_k sh[k]*W[k,j].
__global__ __launch_bounds__(64) void bnparam_kernel(
    const float* __restrict__ stats, const float* __restrict__ gamma,
    const float* __restrict__ beta, const float* __restrict__ W,
    float* __restrict__ outp, int n, int withC) {
  int d = threadIdx.x;
  __shared__ float ssh[64];
  float inv_n = 1.0f / (float)n;
  float mu = stats[d] * inv_n;
  float var = stats[64 + d] * inv_n - mu * mu;
  float r = rsqrtf(var + BN_EPS);
  float s = gamma[d] * r;
  float sh = beta[d] - mu * s;
  outp[d] = s;
  outp[64 + d] = sh;
  ssh[d] = sh;
  __syncthreads();
  if (withC) {
    float c = 0.f;
    for (int k = 0; k < 64; ++k) c = fmaf(ssh[k], W[k * 64 + d], c);
    outp[128 + d] = c;
  }
}

// fused: h_sel = t[idx]*sc1+sh1 (t is f16); out2 = sigmoid(h_sel@Wm+bm)
__global__ __launch_bounds__(256) void selmlp_kernel(
    const f16* __restrict__ t, const int* __restrict__ idx,
    const float* __restrict__ bnp, const float* __restrict__ Wm,
    const float* __restrict__ bm, float* __restrict__ out,
    float* __restrict__ out2, int K) {
  const int lane = threadIdx.x & 63;
  int w = (blockIdx.x * 256 + threadIdx.x) >> 6;
  if (w >= K) return;
  int v = idx[w];
  float hv = fmaf((float)t[(size_t)v * 64 + lane], bnp[lane], bnp[64 + lane]);
  out[(size_t)w * 64 + lane] = hv;
#pragma unroll
  for (int j = 0; j < 5; ++j) {
    float p = hv * Wm[lane * 5 + j];
#pragma unroll
    for (int off = 32; off; off >>= 1) p += __shfl_xor(p, off);
    if (lane == 0) out2[(size_t)w * 5 + j] = 1.f / (1.f + expf(-(p + bm[j])));
  }
}

// ---------------------------------------------------------------------------
extern "C" void kernel_launch(void* const* d_in, const int* in_sizes, int n_in,
                              void* d_out, int out_size, void* d_ws, size_t ws_size,
                              hipStream_t stream) {
  const float* x      = (const float*)d_in[0];
  const int*   eidx   = (const int*)d_in[1];
  const int*   idx    = (const int*)d_in[2];
  const float* W0     = (const float*)d_in[3];
  const float* b0     = (const float*)d_in[4];
  const float* gamma0 = (const float*)d_in[5];
  const float* beta0  = (const float*)d_in[6];
  const float* W1     = (const float*)d_in[7];
  const float* b1     = (const float*)d_in[8];
  const float* gamma1 = (const float*)d_in[9];
  const float* beta1  = (const float*)d_in[10];
  const float* Wm     = (const float*)d_in[11];
  const float* bm     = (const float*)d_in[12];

  const int n = in_sizes[0] / 128;
  const int E = in_sizes[1] / 2;
  const int K = in_sizes[2];
  const int* erow = eidx;      // sources  (edge_index[0])
  const int* ecol = eidx + E;  // targets  (edge_index[1])
  const int nb = (n + 255) / 256;
  const size_t Ecap = (size_t)E + 9 * (size_t)n + 64;  // padded csr capacity
  const int NB = 1024;                                  // gather blocks (A/B: 2048 regressed)

  size_t needed = ((size_t)n + 1) * 64 * 2      // gh (+zero row)
                + (size_t)n * 64 * 2            // t0h (layer act, reused)
                + (size_t)n * 4 * 3             // dis, deg, cursor
                + ((size_t)n + 4) * 4           // pstart
                + Ecap * 4                      // csr (padded)
                + 256 * 4 + 320 * 4             // stats + bnp
                + (size_t)(nb + 4) * 4;         // partial
  if (ws_size < needed) {
    sentinel_kernel<<<dim3((out_size + 255) / 256), dim3(256), 0, stream>>>(
        (float*)d_out, out_size, 1e6f);
    return;
  }
  f16*   gh     = (f16*)d_ws;                     // (n+1)*64 fp16
  f16*   t0h    = gh + ((size_t)n + 1) * 64;      // n*64 fp16 (both layers' act)
  float* dis    = (float*)(t0h + (size_t)n * 64); // n
  int*   deg    = (int*)(dis + n);                // n
  int*   pstart = deg + n;                        // n+4
  int*   cursor = pstart + (n + 4);               // n
  int*   csr    = cursor + n;                     // Ecap
  float* stats  = (float*)(csr + Ecap);           // 256
  float* bnp    = stats + 256;                    // 320
  int*   partial = (int*)(bnp + 320);             // nb+4

  dim3 blk(256);
  const int eb4 = (E + 1023) / 1024;
  const int eb8 = (E + 2047) / 2048;
  const int span = (n + NB - 1) / NB;
  // ---- graph preprocessing ----
  zero_kernel<<<dim3(nb), blk, 0, stream>>>(deg, stats, (unsigned int*)(gh + (size_t)n * 64), n);
  deg_kernel<<<dim3(eb4), blk, 0, stream>>>(ecol, deg, E);
  scan_partial<<<dim3(nb), blk, 0, stream>>>(deg, partial, n);
  scan_top<<<dim3(1), blk, 0, stream>>>(partial, nb);
  scan_final<<<dim3(nb), blk, 0, stream>>>(deg, partial, pstart, cursor, csr, dis, n);
  fill_kernel<<<dim3(eb8), blk, 0, stream>>>(erow, ecol, cursor, csr, E);

  // ---- layer 0 ----
  mfma_gemm<128, false, false><<<dim3(392), blk, 0, stream>>>(
      x, W0, nullptr, nullptr, dis, gh, n);
  gather_post3<<<dim3(NB), blk, 0, stream>>>(gh, csr, pstart, dis, b0, t0h, stats, n, span);
  bnparam_kernel<<<dim3(1), dim3(64), 0, stream>>>(stats, gamma0, beta0, W1, bnp, n, 1);
  // ---- layer 1 (BN0 folded into GEMM) ----
  mfma_gemm<64, true, true><<<dim3(392), blk, 0, stream>>>(
      t0h, W1, bnp, bnp + 128, dis, gh, n);
  gather_post3<<<dim3(NB), blk, 0, stream>>>(gh, csr, pstart, dis, b1, t0h, stats + 128, n, span);
  bnparam_kernel<<<dim3(1), dim3(64), 0, stream>>>(
      stats + 128, gamma1, beta1, nullptr, bnp + 192, n, 0);
  // ---- select + MLP (BN1 folded in) ----
  selmlp_kernel<<<dim3((K + 3) / 4), blk, 0, stream>>>(
      t0h, idx, bnp + 192, Wm, bm, (float*)d_out, (float*)d_out + (size_t)K * 64, K);
}

// Round 17
// 317.604 us; speedup vs baseline: 1.4075x; 1.0565x over previous
//
#include <hip/hip_runtime.h>

static constexpr float NEG_SLOPE = 0.01f;
static constexpr float BN_EPS = 1e-5f;

using f16 = _Float16;
using f16x4 = __attribute__((ext_vector_type(4))) _Float16;
using f16x8 = __attribute__((ext_vector_type(8))) _Float16;
using f32x4 = __attribute__((ext_vector_type(4))) float;

// ---------------------------------------------------------------------------
__global__ __launch_bounds__(256) void sentinel_kernel(float* out, int m, float val) {
  int i = blockIdx.x * 256 + threadIdx.x;
  if (i < m) out[i] = val;
}

// zero deg (n ints) + stats (256 floats) + the zero-row of g (row n, 128 B)
__global__ __launch_bounds__(256) void zero_kernel(int* __restrict__ deg,
                                                   float* __restrict__ stats,
                                                   unsigned int* __restrict__ gzero, int n) {
  int stride = gridDim.x * blockDim.x;
  for (int i = blockIdx.x * blockDim.x + threadIdx.x; i < n; i += stride) deg[i] = 0;
  if (blockIdx.x == 0 && threadIdx.x < 256) stats[threadIdx.x] = 0.f;
  if (blockIdx.x == 0 && threadIdx.x < 32) gzero[threadIdx.x] = 0u;
}

// deg[v] += 1 per incoming edge; 4 independent edges per thread
__global__ __launch_bounds__(256) void deg_kernel(const int* __restrict__ col,
                                                  int* __restrict__ deg, int E) {
  int t = blockIdx.x * 256 + threadIdx.x;
  int S = gridDim.x * 256;
  int e0 = t, e1 = t + S, e2 = t + 2 * S, e3 = t + 3 * S;
  int v0 = (e0 < E) ? col[e0] : -1;
  int v1 = (e1 < E) ? col[e1] : -1;
  int v2 = (e2 < E) ? col[e2] : -1;
  int v3 = (e3 < E) ? col[e3] : -1;
  if (v0 >= 0) atomicAdd(&deg[v0], 1);
  if (v1 >= 0) atomicAdd(&deg[v1], 1);
  if (v2 >= 0) atomicAdd(&deg[v2], 1);
  if (v3 >= 0) atomicAdd(&deg[v3], 1);
}

// ---------------------------------------------------------------------------
// 3-phase exclusive scan over padded degrees pd=(d+1+7)&~7 (self included).
__global__ __launch_bounds__(256) void scan_partial(const int* __restrict__ deg,
                                                    int* __restrict__ partial, int n) {
  int i = blockIdx.x * 256 + threadIdx.x;
  int d = (i < n) ? deg[i] : 0;
  int pd = (i < n) ? ((d + 8) & ~7) : 0;
  __shared__ int s[256];
  s[threadIdx.x] = pd;
  __syncthreads();
  for (int off = 128; off; off >>= 1) {
    if (threadIdx.x < off) s[threadIdx.x] += s[threadIdx.x + off];
    __syncthreads();
  }
  if (threadIdx.x == 0) partial[blockIdx.x] = s[0];
}

__global__ __launch_bounds__(256) void scan_top(int* partial, int nb) {
  __shared__ int s[256];
  __shared__ int carry_s;
  if (threadIdx.x == 0) carry_s = 0;
  __syncthreads();
  for (int base = 0; base < nb; base += 256) {
    int i = base + threadIdx.x;
    int v = (i < nb) ? partial[i] : 0;
    s[threadIdx.x] = v;
    __syncthreads();
    for (int off = 1; off < 256; off <<= 1) {
      int t = (threadIdx.x >= off) ? s[threadIdx.x - off] : 0;
      __syncthreads();
      s[threadIdx.x] += t;
      __syncthreads();
    }
    int inc = s[threadIdx.x];
    int tot = s[255];
    int carry = carry_s;
    if (i < nb) partial[i] = carry + inc - v;
    __syncthreads();
    if (threadIdx.x == 0) carry_s = carry + tot;
    __syncthreads();
  }
}

// pstart/cursor/dis + write self-loop & pad entries into csr
__global__ __launch_bounds__(256) void scan_final(const int* __restrict__ deg,
                                                  const int* __restrict__ partial,
                                                  int* __restrict__ pstart,
                                                  int* __restrict__ cursor,
                                                  int* __restrict__ csr,
                                                  float* __restrict__ dis, int n) {
  int i = blockIdx.x * 256 + threadIdx.x;
  int d = (i < n) ? deg[i] : 0;
  int pd = (i < n) ? ((d + 8) & ~7) : 0;
  __shared__ int s[256];
  s[threadIdx.x] = pd;
  __syncthreads();
  for (int off = 1; off < 256; off <<= 1) {
    int t = (threadIdx.x >= off) ? s[threadIdx.x - off] : 0;
    __syncthreads();
    s[threadIdx.x] += t;
    __syncthreads();
  }
  if (i < n) {
    int incl = partial[blockIdx.x] + s[threadIdx.x];
    int ps = incl - pd;
    pstart[i] = ps;
    cursor[i] = ps + d;          // neighbors land in [ps, ps+d)
    dis[i] = rsqrtf((float)(d + 1));
    csr[ps + d] = i;             // self loop
    for (int j = d + 1; j < pd; ++j) csr[ps + j] = n;  // pads -> zero row
    if (i == n - 1) pstart[n] = incl;
  }
}

// ---------------------------------------------------------------------------
// GEMM body: g[r,c] = ((A[r,:](*sc) @ W[:,c]) + cadd[c]) * dis[r], fp16 out.
template <int KD, bool FOLD, bool A_HALF>
__device__ __forceinline__ void gemm_body(
    int bid, int nblocks,
    const void* __restrict__ Aptr, const float* __restrict__ W,
    const float* __restrict__ sc, const float* __restrict__ cadd,
    const float* __restrict__ dis, f16* __restrict__ g, int n) {
  constexpr int NKT = KD / 16;
  const int lane = threadIdx.x & 63;
  const int wq = threadIdx.x >> 6;
  const int lr = lane & 15;
  const int kb = (lane >> 4) * 4;

  f16x4 bfrag[NKT][4];
#pragma unroll
  for (int kt = 0; kt < NKT; ++kt)
#pragma unroll
    for (int ct = 0; ct < 4; ++ct) {
#pragma unroll
      for (int j = 0; j < 4; ++j) {
        int k = kt * 16 + kb + j;
        float w = W[k * 64 + ct * 16 + lr];
        if (FOLD) w *= sc[k];
        bfrag[kt][ct][j] = (f16)w;
      }
    }
  float cl[4];
#pragma unroll
  for (int ct = 0; ct < 4; ++ct) cl[ct] = FOLD ? cadd[ct * 16 + lr] : 0.f;

  const int ntiles = (n + 15) >> 4;
  for (int t = bid * 4 + wq; t < ntiles; t += nblocks * 4) {
    const int r0 = t << 4;
    int arow = r0 + lr;
    if (arow >= n) arow = n - 1;
    f16x4 afrag[NKT];
    if (A_HALF) {
      const f16* Ah = (const f16*)Aptr;
#pragma unroll
      for (int kt = 0; kt < NKT; ++kt)
        afrag[kt] = *reinterpret_cast<const f16x4*>(Ah + (size_t)arow * KD + kt * 16 + kb);
    } else {
      const float* Af = (const float*)Aptr;
#pragma unroll
      for (int kt = 0; kt < NKT; ++kt) {
        f32x4 xa = *reinterpret_cast<const f32x4*>(Af + (size_t)arow * KD + kt * 16 + kb);
        f16x4 a;
        a[0] = (f16)xa[0]; a[1] = (f16)xa[1]; a[2] = (f16)xa[2]; a[3] = (f16)xa[3];
        afrag[kt] = a;
      }
    }
    f32x4 acc[4];
#pragma unroll
    for (int ct = 0; ct < 4; ++ct) acc[ct] = (f32x4){0.f, 0.f, 0.f, 0.f};
#pragma unroll
    for (int kt = 0; kt < NKT; ++kt)
#pragma unroll
      for (int ct = 0; ct < 4; ++ct)
        acc[ct] = __builtin_amdgcn_mfma_f32_16x16x16f16(afrag[kt], bfrag[kt][ct], acc[ct], 0, 0, 0);
    if (r0 + 16 <= n) {
#pragma unroll
      for (int v = 0; v < 4; ++v) {
        int grow = r0 + (lane >> 4) * 4 + v;
        float dv = dis[grow];
#pragma unroll
        for (int ct = 0; ct < 4; ++ct)
          g[(size_t)grow * 64 + ct * 16 + lr] = (f16)((acc[ct][v] + cl[ct]) * dv);
      }
    } else {
      for (int v = 0; v < 4; ++v) {
        int grow = r0 + (lane >> 4) * 4 + v;
        if (grow < n) {
          float dv = dis[grow];
          for (int ct = 0; ct < 4; ++ct)
            g[(size_t)grow * 64 + ct * 16 + lr] = (f16)((acc[ct][v] + cl[ct]) * dv);
        }
      }
    }
  }
}

// fill body: csr[--cursor[v]] = row[e]; 8 independent edges per thread
__device__ __forceinline__ void fill_body(
    int bid, int nblocks,
    const int* __restrict__ row, const int* __restrict__ colv,
    int* __restrict__ cursor, int* __restrict__ csr, int E) {
  int t = bid * 256 + threadIdx.x;
  int S = nblocks * 256;
  int vv[8], rr[8], oo[8];
  bool bb[8];
#pragma unroll
  for (int j = 0; j < 8; ++j) {
    int e = t + j * S;
    bb[j] = e < E;
    if (bb[j]) { vv[j] = colv[e]; rr[j] = row[e]; }
  }
#pragma unroll
  for (int j = 0; j < 8; ++j)
    if (bb[j]) oo[j] = atomicSub(&cursor[vv[j]], 1) - 1;
#pragma unroll
  for (int j = 0; j < 8; ++j)
    if (bb[j]) csr[oo[j]] = rr[j];
}

// fused: blocks [0,GB) run layer-0 GEMM; blocks [GB, gridDim) run csr fill.
// The two are data-independent; co-scheduling hides the GEMM under the
// fill's write-allocate wall.
__global__ __launch_bounds__(256) void fused_gemm_fill(
    const float* __restrict__ X, const float* __restrict__ W0,
    const float* __restrict__ dis, f16* __restrict__ g, int n,
    const int* __restrict__ row, const int* __restrict__ colv,
    int* __restrict__ cursor, int* __restrict__ csr, int E, int GB) {
  if ((int)blockIdx.x < GB)
    gemm_body<128, false, false>(blockIdx.x, GB, X, W0, nullptr, nullptr, dis, g, n);
  else
    fill_body(blockIdx.x - GB, gridDim.x - GB, row, colv, cursor, csr, E);
}

// standalone GEMM (layer 1)
template <int KD, bool FOLD, bool A_HALF>
__global__ __launch_bounds__(256) void mfma_gemm(
    const void* __restrict__ Aptr, const float* __restrict__ W,
    const float* __restrict__ sc, const float* __restrict__ cadd,
    const float* __restrict__ dis, f16* __restrict__ g, int n) {
  gemm_body<KD, FOLD, A_HALF>(blockIdx.x, gridDim.x, Aptr, W, sc, cadd, dis, g, n);
}

// ---------------------------------------------------------------------------
// Octet gather: 8 lanes x 16B (f16x8) per row -> one instr gathers 8 rows.
// CSR includes self-loop and zero-row pads; no masking in the inner loop.
// t[v] = leaky(dis[v]*sum + bias) stored f16; stats via block reduce + atomics.
__global__ __launch_bounds__(256) void gather_post3(
    const f16* __restrict__ g, const int* __restrict__ csr,
    const int* __restrict__ pstart, const float* __restrict__ dis,
    const float* __restrict__ bias, f16* __restrict__ t_out,
    float* __restrict__ stats, int n, int span) {
  const int tid = threadIdx.x;
  const int w = tid >> 6;
  const int lane = tid & 63;
  const int grp = lane >> 3;  // row slot 0..7
  const int q = lane & 7;     // 16B sub-slot: features q*8 .. q*8+7
  float bias8[8];
#pragma unroll
  for (int j = 0; j < 8; ++j) bias8[j] = bias[q * 8 + j];
  float sum8[8], sq8[8];
#pragma unroll
  for (int j = 0; j < 8; ++j) { sum8[j] = 0.f; sq8[j] = 0.f; }

  const int v0 = blockIdx.x * span;
  const int vend = (v0 + span < n) ? v0 + span : n;
  for (int v = v0 + w; v < vend; v += 4) {
    const int ps = pstart[v];
    const int pe = pstart[v + 1];
    float acc[8];
#pragma unroll
    for (int j = 0; j < 8; ++j) acc[j] = 0.f;
    int e = ps;
    for (; e + 8 < pe; e += 16) {
      int ua = csr[e + grp];
      int ub = csr[e + 8 + grp];
      f16x8 da = *reinterpret_cast<const f16x8*>(g + (size_t)ua * 64 + q * 8);
      f16x8 db = *reinterpret_cast<const f16x8*>(g + (size_t)ub * 64 + q * 8);
#pragma unroll
      for (int j = 0; j < 8; ++j) acc[j] += (float)da[j] + (float)db[j];
    }
    if (e < pe) {
      int u = csr[e + grp];
      f16x8 d = *reinterpret_cast<const f16x8*>(g + (size_t)u * 64 + q * 8);
#pragma unroll
      for (int j = 0; j < 8; ++j) acc[j] += (float)d[j];
    }
    // reduce across the 8 row-groups (xor over lane bits 3..5)
#pragma unroll
    for (int j = 0; j < 8; ++j) acc[j] += __shfl_xor(acc[j], 8);
#pragma unroll
    for (int j = 0; j < 8; ++j) acc[j] += __shfl_xor(acc[j], 16);
#pragma unroll
    for (int j = 0; j < 8; ++j) acc[j] += __shfl_xor(acc[j], 32);
    if (grp == 0) {
      float dv = dis[v];
      f16x8 o;
#pragma unroll
      for (int j = 0; j < 8; ++j) {
        float x = dv * acc[j] + bias8[j];
        x = (x > 0.f) ? x : NEG_SLOPE * x;
        o[j] = (f16)x;
        sum8[j] += x;
        sq8[j] += x * x;
      }
      *reinterpret_cast<f16x8*>(t_out + (size_t)v * 64 + q * 8) = o;
    }
  }
  __shared__ float sm[4][128];
  if (grp == 0) {
#pragma unroll
    for (int j = 0; j < 8; ++j) {
      sm[w][q * 8 + j] = sum8[j];
      sm[w][64 + q * 8 + j] = sq8[j];
    }
  }
  __syncthreads();
  if (tid < 128)
    atomicAdd(&stats[tid], sm[0][tid] + sm[1][tid] + sm[2][tid] + sm[3][tid]);
}

// ---------------------------------------------------------------------------
// BN fold params from stats: sc, sh; optionally c[j] = sum_k sh[k]*W[k,j].
__global__ __launch_bounds__(64) void bnparam_kernel(
    const float* __restrict__ stats, const float* __restrict__ gamma,
    const float* __restrict__ beta, const float* __restrict__ W,
    float* __restrict__ outp, int n, int withC) {
  int d = threadIdx.x;
  __shared__ float ssh[64];
  float inv_n = 1.0f / (float)n;
  float mu = stats[d] * inv_n;
  float var = stats[64 + d] * inv_n - mu * mu;
  float r = rsqrtf(var + BN_EPS);
  float s = gamma[d] * r;
  float sh = beta[d] - mu * s;
  outp[d] = s;
  outp[64 + d] = sh;
  ssh[d] = sh;
  __syncthreads();
  if (withC) {
    float c = 0.f;
    for (int k = 0; k < 64; ++k) c = fmaf(ssh[k], W[k * 64 + d], c);
    outp[128 + d] = c;
  }
}

// fused: h_sel = t[idx]*sc1+sh1 (t is f16); out2 = sigmoid(h_sel@Wm+bm)
__global__ __launch_bounds__(256) void selmlp_kernel(
    const f16* __restrict__ t, const int* __restrict__ idx,
    const float* __restrict__ bnp, const float* __restrict__ Wm,
    const float* __restrict__ bm, float* __restrict__ out,
    float* __restrict__ out2, int K) {
  const int lane = threadIdx.x & 63;
  int w = (blockIdx.x * 256 + threadIdx.x) >> 6;
  if (w >= K) return;
  int v = idx[w];
  float hv = fmaf((float)t[(size_t)v * 64 + lane], bnp[lane], bnp[64 + lane]);
  out[(size_t)w * 64 + lane] = hv;
#pragma unroll
  for (int j = 0; j < 5; ++j) {
    float p = hv * Wm[lane * 5 + j];
#pragma unroll
    for (int off = 32; off; off >>= 1) p += __shfl_xor(p, off);
    if (lane == 0) out2[(size_t)w * 5 + j] = 1.f / (1.f + expf(-(p + bm[j])));
  }
}

// ---------------------------------------------------------------------------
extern "C" void kernel_launch(void* const* d_in, const int* in_sizes, int n_in,
                              void* d_out, int out_size, void* d_ws, size_t ws_size,
                              hipStream_t stream) {
  const float* x      = (const float*)d_in[0];
  const int*   eidx   = (const int*)d_in[1];
  const int*   idx    = (const int*)d_in[2];
  const float* W0     = (const float*)d_in[3];
  const float* b0     = (const float*)d_in[4];
  const float* gamma0 = (const float*)d_in[5];
  const float* beta0  = (const float*)d_in[6];
  const float* W1     = (const float*)d_in[7];
  const float* b1     = (const float*)d_in[8];
  const float* gamma1 = (const float*)d_in[9];
  const float* beta1  = (const float*)d_in[10];
  const float* Wm     = (const float*)d_in[11];
  const float* bm     = (const float*)d_in[12];

  const int n = in_sizes[0] / 128;
  const int E = in_sizes[1] / 2;
  const int K = in_sizes[2];
  const int* erow = eidx;      // sources  (edge_index[0])
  const int* ecol = eidx + E;  // targets  (edge_index[1])
  const int nb = (n + 255) / 256;
  const size_t Ecap = (size_t)E + 9 * (size_t)n + 64;  // padded csr capacity
  const int NB = 1024;                                  // gather blocks

  size_t needed = ((size_t)n + 1) * 64 * 2      // gh (+zero row)
                + (size_t)n * 64 * 2            // t0h (layer act, reused)
                + (size_t)n * 4 * 3             // dis, deg, cursor
                + ((size_t)n + 4) * 4           // pstart
                + Ecap * 4                      // csr (padded)
                + 256 * 4 + 320 * 4             // stats + bnp
                + (size_t)(nb + 4) * 4;         // partial
  if (ws_size < needed) {
    sentinel_kernel<<<dim3((out_size + 255) / 256), dim3(256), 0, stream>>>(
        (float*)d_out, out_size, 1e6f);
    return;
  }
  f16*   gh     = (f16*)d_ws;                     // (n+1)*64 fp16
  f16*   t0h    = gh + ((size_t)n + 1) * 64;      // n*64 fp16 (both layers' act)
  float* dis    = (float*)(t0h + (size_t)n * 64); // n
  int*   deg    = (int*)(dis + n);                // n
  int*   pstart = deg + n;                        // n+4
  int*   cursor = pstart + (n + 4);               // n
  int*   csr    = cursor + n;                     // Ecap
  float* stats  = (float*)(csr + Ecap);           // 256
  float* bnp    = stats + 256;                    // 320
  int*   partial = (int*)(bnp + 320);             // nb+4

  dim3 blk(256);
  const int eb4 = (E + 1023) / 1024;
  const int eb8 = (E + 2047) / 2048;   // fill blocks
  const int GB = 392;                  // gemm blocks in fused launch
  const int span = (n + NB - 1) / NB;
  // ---- graph preprocessing ----
  zero_kernel<<<dim3(nb), blk, 0, stream>>>(deg, stats, (unsigned int*)(gh + (size_t)n * 64), n);
  deg_kernel<<<dim3(eb4), blk, 0, stream>>>(ecol, deg, E);
  scan_partial<<<dim3(nb), blk, 0, stream>>>(deg, partial, n);
  scan_top<<<dim3(1), blk, 0, stream>>>(partial, nb);
  scan_final<<<dim3(nb), blk, 0, stream>>>(deg, partial, pstart, cursor, csr, dis, n);

  // ---- fused: csr fill + layer-0 GEMM (independent; co-scheduled) ----
  fused_gemm_fill<<<dim3(GB + eb8), blk, 0, stream>>>(
      x, W0, dis, gh, n, erow, ecol, cursor, csr, E, GB);

  // ---- layer 0 aggregation ----
  gather_post3<<<dim3(NB), blk, 0, stream>>>(gh, csr, pstart, dis, b0, t0h, stats, n, span);
  bnparam_kernel<<<dim3(1), dim3(64), 0, stream>>>(stats, gamma0, beta0, W1, bnp, n, 1);
  // ---- layer 1 (BN0 folded into GEMM) ----
  mfma_gemm<64, true, true><<<dim3(392), blk, 0, stream>>>(
      t0h, W1, bnp, bnp + 128, dis, gh, n);
  gather_post3<<<dim3(NB), blk, 0, stream>>>(gh, csr, pstart, dis, b1, t0h, stats + 128, n, span);
  bnparam_kernel<<<dim3(1), dim3(64), 0, stream>>>(
      stats + 128, gamma1, beta1, nullptr, bnp + 192, n, 0);
  // ---- select + MLP (BN1 folded in) ----
  selmlp_kernel<<<dim3((K + 3) / 4), blk, 0, stream>>>(
      t0h, idx, bnp + 192, Wm, bm, (float*)d_out, (float*)d_out + (size_t)K * 64, K);
}